// Round 6
// baseline (1368.642 us; speedup 1.0000x reference)
//
#include <hip/hip_runtime.h>

#define N_NODES  50000
#define E_EDGES  800000
#define E_TOT    850000   // E + N self-loops
#define H_HEADS  2
#define C_DIM    64
#define HC       128
#define L_LAYERS 3
#define OUT_DIM  128
#define G_GRAPHS 512
#define NEG_SLOPE 0.2f
#define SCAN_B   196      // ceil(N/256)

__device__ __forceinline__ void lds_fence() { asm volatile("" ::: "memory"); }

// ---- h[n][c] = embed[x[n]][c] ----
__global__ void embed_kernel(const int* __restrict__ x, const float* __restrict__ embed,
                             float* __restrict__ h) {
    int i = blockIdx.x * 256 + threadIdx.x;
    if (i >= N_NODES * C_DIM) return;
    int n = i >> 6, c = i & 63;
    h[i] = embed[x[n] * C_DIM + c];
}

// ---- CSR build ----
__global__ void csr_zero_kernel(int* __restrict__ counts) {
    int i = blockIdx.x * 256 + threadIdx.x;
    if (i < N_NODES) counts[i] = 0;
}

__global__ void csr_count_kernel(const int* __restrict__ dsts, int* __restrict__ counts) {
    int e = blockIdx.x * 256 + threadIdx.x;
    if (e >= E_TOT) return;
    int d = (e < E_EDGES) ? dsts[e] : e - E_EDGES;
    atomicAdd(&counts[d], 1);
}

__global__ void scan_partial_kernel(const int* __restrict__ counts, int* __restrict__ row_ptr,
                                    int* __restrict__ partials) {
    __shared__ int wsum[4];
    int i = blockIdx.x * 256 + threadIdx.x;
    int lane = threadIdx.x & 63, wid = threadIdx.x >> 6;
    int cnt = (i < N_NODES) ? counts[i] : 0;
    int v = cnt;
#pragma unroll
    for (int off = 1; off < 64; off <<= 1) {
        int t = __shfl_up(v, off, 64);
        if (lane >= off) v += t;
    }
    if (lane == 63) wsum[wid] = v;
    __syncthreads();
    int woff = 0;
#pragma unroll
    for (int w = 0; w < 4; w++) if (w < wid) woff += wsum[w];
    v += woff;
    if (i < N_NODES) row_ptr[i] = v - cnt;
    if (threadIdx.x == 255) partials[blockIdx.x] = v;
}

__global__ void scan_offsets_kernel(const int* __restrict__ partials, int* __restrict__ block_off) {
    __shared__ int wsum[4];
    int tid = threadIdx.x;
    int lane = tid & 63, wid = tid >> 6;
    int cnt = (tid < SCAN_B) ? partials[tid] : 0;
    int v = cnt;
#pragma unroll
    for (int off = 1; off < 64; off <<= 1) {
        int t = __shfl_up(v, off, 64);
        if (lane >= off) v += t;
    }
    if (lane == 63) wsum[wid] = v;
    __syncthreads();
    int woff = 0;
#pragma unroll
    for (int w = 0; w < 4; w++) if (w < wid) woff += wsum[w];
    v += woff;
    if (tid < SCAN_B) block_off[tid] = v - cnt;
}

__global__ void scan_add_kernel(int* __restrict__ row_ptr, const int* __restrict__ block_off,
                                int* __restrict__ write_off) {
    int i = blockIdx.x * 256 + threadIdx.x;
    if (i < N_NODES) {
        int v = row_ptr[i] + block_off[blockIdx.x];
        row_ptr[i] = v;
        write_off[i] = v;
    }
    if (i == 0) row_ptr[N_NODES] = E_TOT;
}

__global__ void csr_scatter_kernel(const int* __restrict__ srcs, const int* __restrict__ dsts,
                                   int* __restrict__ write_off, int* __restrict__ src_sorted) {
    int e = blockIdx.x * 256 + threadIdx.x;
    if (e >= E_TOT) return;
    int s, d;
    if (e < E_EDGES) { s = srcs[e]; d = dsts[e]; }
    else             { s = d = e - E_EDGES; }
    int pos = atomicAdd(&write_off[d], 1);
    src_sorted[pos] = s;
}

// ---- fused per-layer linears: h2 = relu(h@W+b); xl = h2@Wl+bl; xr = h2@Wr+br. ----
__global__ void layer_lin_kernel(const float* __restrict__ h,
                                 const float* __restrict__ W, const float* __restrict__ b,
                                 const float* __restrict__ Wl, const float* __restrict__ bl,
                                 const float* __restrict__ Wr, const float* __restrict__ br,
                                 float* __restrict__ xli, float* __restrict__ xri) {
    __shared__ __align__(16) float sH[16 * 64];
    __shared__ __align__(16) float sH2[16 * 64];
    int tid = threadIdx.x;
    int base = blockIdx.x * 16;
#pragma unroll
    for (int i = 0; i < 4; i++) {
        int idx = tid + i * 256;
        int nn = base + (idx >> 6);
        sH[idx] = (nn < N_NODES) ? h[(size_t)nn * 64 + (idx & 63)] : 0.f;
    }
    __syncthreads();
    {
        int c = tid & 63, g = tid >> 6;
        float a0 = b[c], a1 = a0, a2 = a0, a3 = a0;
        for (int k = 0; k < 64; k += 4) {
            float w0 = W[k * 64 + c], w1 = W[(k + 1) * 64 + c];
            float w2 = W[(k + 2) * 64 + c], w3 = W[(k + 3) * 64 + c];
            float4 h0 = *(const float4*)&sH[(g * 4 + 0) * 64 + k];
            float4 h1 = *(const float4*)&sH[(g * 4 + 1) * 64 + k];
            float4 h2 = *(const float4*)&sH[(g * 4 + 2) * 64 + k];
            float4 h3 = *(const float4*)&sH[(g * 4 + 3) * 64 + k];
            a0 = fmaf(h0.x, w0, fmaf(h0.y, w1, fmaf(h0.z, w2, fmaf(h0.w, w3, a0))));
            a1 = fmaf(h1.x, w0, fmaf(h1.y, w1, fmaf(h1.z, w2, fmaf(h1.w, w3, a1))));
            a2 = fmaf(h2.x, w0, fmaf(h2.y, w1, fmaf(h2.z, w2, fmaf(h2.w, w3, a2))));
            a3 = fmaf(h3.x, w0, fmaf(h3.y, w1, fmaf(h3.z, w2, fmaf(h3.w, w3, a3))));
        }
        sH2[(g * 4 + 0) * 64 + c] = fmaxf(a0, 0.f);
        sH2[(g * 4 + 1) * 64 + c] = fmaxf(a1, 0.f);
        sH2[(g * 4 + 2) * 64 + c] = fmaxf(a2, 0.f);
        sH2[(g * 4 + 3) * 64 + c] = fmaxf(a3, 0.f);
    }
    __syncthreads();
    {
        int j = tid & 127, gg = tid >> 7;
        float accl[8], accr[8];
#pragma unroll
        for (int n = 0; n < 8; n++) { accl[n] = bl[j]; accr[n] = br[j]; }
        for (int k = 0; k < 64; k += 4) {
            float wl0 = Wl[k * 128 + j], wl1 = Wl[(k + 1) * 128 + j];
            float wl2 = Wl[(k + 2) * 128 + j], wl3 = Wl[(k + 3) * 128 + j];
            float wr0 = Wr[k * 128 + j], wr1 = Wr[(k + 1) * 128 + j];
            float wr2 = Wr[(k + 2) * 128 + j], wr3 = Wr[(k + 3) * 128 + j];
#pragma unroll
            for (int n = 0; n < 8; n++) {
                float4 hv = *(const float4*)&sH2[(gg * 8 + n) * 64 + k];
                accl[n] = fmaf(hv.x, wl0, fmaf(hv.y, wl1, fmaf(hv.z, wl2, fmaf(hv.w, wl3, accl[n]))));
                accr[n] = fmaf(hv.x, wr0, fmaf(hv.y, wr1, fmaf(hv.z, wr2, fmaf(hv.w, wr3, accr[n]))));
            }
        }
        int hh = j >> 6, c = j & 63;
#pragma unroll
        for (int n = 0; n < 8; n++) {
            int node = base + gg * 8 + n;
            if (node < N_NODES) {
                size_t o = (size_t)node * 128 + c * 2 + hh;
                xli[o] = accl[n];
                xri[o] = accr[n];
            }
        }
    }
}

// ---- Ql[n][h] = sum_c leaky(a_hc * xl[n,h,c]) — node-separable softmax-shift bound ----
__global__ void ql_kernel(const float2* __restrict__ xl2, const float* __restrict__ att,
                          float2* __restrict__ Ql) {
    int w = threadIdx.x >> 6;
    int n = blockIdx.x * 4 + w;
    if (n >= N_NODES) return;
    int lane = threadIdx.x & 63;
    float2 v = xl2[(size_t)n * 64 + lane];
    float px = att[lane] * v.x, py = att[64 + lane] * v.y;
    float qx = fmaxf(px, NEG_SLOPE * px);   // leaky(p) = 0.6p + 0.4|p|
    float qy = fmaxf(py, NEG_SLOPE * py);
#pragma unroll
    for (int off = 32; off; off >>= 1) {
        qx += __shfl_xor(qx, off, 64);
        qy += __shfl_xor(qy, off, 64);
    }
    if (lane == 0) Ql[n] = make_float2(qx, qy);
}

// ---- GATv2 edge phase: one wave per dst node, lane = channel, float2 = both heads.
// Softmax shift m = Qr[d] + max_in Ql[s] precomputed -> no online rescale, no max pass. ----
__global__ void gat_kernel(const float2* __restrict__ xl2, const float2* __restrict__ xr2,
                           const float* __restrict__ att, const int* __restrict__ row_ptr,
                           const int* __restrict__ src_sorted, const float2* __restrict__ Ql,
                           const float* __restrict__ bias, float* __restrict__ h_out) {
    __shared__ __align__(16) float cbuf[4][8 * 132];
    __shared__ float2 wbuf[4][8];
    int w = threadIdx.x >> 6;
    int d = blockIdx.x * 4 + w;
    if (d >= N_NODES) return;
    int lane = threadIdx.x & 63;
    int r0 = row_ptr[d], r1 = row_ptr[d + 1];
    float2 vr = xr2[(size_t)d * 64 + lane];
    float ax = att[lane], ay = att[64 + lane];
    float* cb = cbuf[w];
    float2* wb = wbuf[w];
    int e_of = lane >> 3, p = lane & 7;

    // Qr[d] = sum_c leaky(a_c * vr_c) per head (upper-bound piece of dst)
    float prx = ax * vr.x, pry = ay * vr.y;
    float qrx = fmaxf(prx, NEG_SLOPE * prx);
    float qry = fmaxf(pry, NEG_SLOPE * pry);
    // max of Ql over incoming srcs
    float mqx = -INFINITY, mqy = -INFINITY;
    for (int base = r0; base < r1; base += 64) {
        int a = base + lane;
        if (a < r1) {
            float2 q = Ql[src_sorted[a]];
            mqx = fmaxf(mqx, q.x);
            mqy = fmaxf(mqy, q.y);
        }
    }
#pragma unroll
    for (int off = 32; off; off >>= 1) {
        qrx += __shfl_xor(qrx, off, 64);
        qry += __shfl_xor(qry, off, 64);
        mqx = fmaxf(mqx, __shfl_xor(mqx, off, 64));
        mqy = fmaxf(mqy, __shfl_xor(mqy, off, 64));
    }
    float mx = mqx + qrx, my = mqy + qry;   // guaranteed >= every incoming score

    float dpx = 0.f, dpy = 0.f;
    float accx = 0.f, accy = 0.f;

    for (int base = r0; base < r1; base += 64) {
        int a = base + lane;
        int idx = src_sorted[(a < r1) ? a : (r1 - 1)];
        for (int cbase = 0; cbase < 64 && base + cbase < r1; cbase += 8) {
            int rem = r1 - base - cbase;
            float2 vl[8];
#pragma unroll
            for (int e = 0; e < 8; e++) {
                int sv = __builtin_amdgcn_readlane(idx, cbase + e);
                int s = (e < rem) ? sv : d;
                vl[e] = xl2[(size_t)s * 64 + lane];
            }
#pragma unroll
            for (int e = 0; e < 8; e++) {
                float vx = vl[e].x + vr.x, vy = vl[e].y + vr.y;
                vx = fmaxf(vx, vx * NEG_SLOPE);
                vy = fmaxf(vy, vy * NEG_SLOPE);
                *(float2*)&cb[e * 132 + 2 * lane] = make_float2(vx * ax, vy * ay);
            }
            lds_fence();
            float sx = 0.f, sy = 0.f;
            {
                const float4* row = (const float4*)&cb[e_of * 132 + p * 16];
#pragma unroll
                for (int j = 0; j < 4; j++) {
                    float4 f = row[j];
                    sx += f.x + f.z;
                    sy += f.y + f.w;
                }
            }
            lds_fence();
#pragma unroll
            for (int off = 1; off <= 4; off <<= 1) {
                sx += __shfl_xor(sx, off, 64);
                sy += __shfl_xor(sy, off, 64);
            }
            if (e_of >= rem) { sx = -INFINITY; sy = -INFINITY; }  // exp -> 0
            float wx = __expf(sx - mx), wy = __expf(sy - my);
            dpx += wx; dpy += wy;
            if (p == 0) wb[e_of] = make_float2(wx, wy);
            lds_fence();
#pragma unroll
            for (int e = 0; e < 8; e++) {
                float2 wv = wb[e];
                accx = fmaf(wv.x, vl[e].x, accx);
                accy = fmaf(wv.y, vl[e].y, accy);
            }
            lds_fence();
        }
    }
#pragma unroll
    for (int off = 32; off; off >>= 1) {
        dpx += __shfl_xor(dpx, off, 64);
        dpy += __shfl_xor(dpy, off, 64);
    }
    h_out[(size_t)d * 64 + lane] = (accx / dpx + accy / dpy) * 4.0f + bias[lane];
}

__global__ void zero_out_kernel(float* __restrict__ out) {
    int i = blockIdx.x * 256 + threadIdx.x;
    if (i < G_GRAPHS * OUT_DIM) out[i] = 0.f;
}

// ---- readout GEMM fused with per-graph segment sum; batch-sorted run grouping ----
__global__ void readout_kernel(const float* __restrict__ h, const float* __restrict__ W,
                               const float* __restrict__ b, const int* __restrict__ batch,
                               float* __restrict__ out) {
    __shared__ __align__(16) float sH[16 * 64];
    __shared__ int sB[16];
    int tid = threadIdx.x;
    int base = blockIdx.x * 16;
#pragma unroll
    for (int i = 0; i < 4; i++) {
        int idx = tid + i * 256;
        int nn = base + (idx >> 6);
        sH[idx] = (nn < N_NODES) ? h[(size_t)nn * 64 + (idx & 63)] : 0.f;
    }
    if (tid < 16) sB[tid] = (base + tid < N_NODES) ? batch[base + tid] : -1;
    __syncthreads();
    int j = tid & 127, gg = tid >> 7;
    float acc[8];
#pragma unroll
    for (int n = 0; n < 8; n++) acc[n] = b[j];
    for (int k = 0; k < 64; k += 4) {
        float w0 = W[k * OUT_DIM + j], w1 = W[(k + 1) * OUT_DIM + j];
        float w2 = W[(k + 2) * OUT_DIM + j], w3 = W[(k + 3) * OUT_DIM + j];
#pragma unroll
        for (int n = 0; n < 8; n++) {
            float4 hv = *(const float4*)&sH[(gg * 8 + n) * 64 + k];
            acc[n] = fmaf(hv.x, w0, fmaf(hv.y, w1, fmaf(hv.z, w2, fmaf(hv.w, w3, acc[n]))));
        }
    }
    float run = 0.f; int curb = -2;
#pragma unroll
    for (int n = 0; n < 8; n++) {
        int node = base + gg * 8 + n;
        int bb = (node < N_NODES) ? sB[gg * 8 + n] : -1;
        if (bb != curb) {
            if (curb >= 0) atomicAdd(&out[curb * OUT_DIM + j], run);
            run = 0.f; curb = bb;
        }
        if (bb >= 0) run += acc[n];
    }
    if (curb >= 0) atomicAdd(&out[curb * OUT_DIM + j], run);
}

extern "C" void kernel_launch(void* const* d_in, const int* in_sizes, int n_in,
                              void* d_out, int out_size, void* d_ws, size_t ws_size,
                              hipStream_t stream) {
    const int*   x        = (const int*)d_in[0];
    const int*   edge     = (const int*)d_in[1];
    const int*   batch    = (const int*)d_in[2];
    const float* embed    = (const float*)d_in[4];
    const float* lin_W    = (const float*)d_in[5];
    const float* lin_b    = (const float*)d_in[6];
    const float* gat_Wl   = (const float*)d_in[7];
    const float* gat_bl   = (const float*)d_in[8];
    const float* gat_Wr   = (const float*)d_in[9];
    const float* gat_br   = (const float*)d_in[10];
    const float* gat_att  = (const float*)d_in[11];
    const float* gat_bias = (const float*)d_in[12];
    const float* ro_W     = (const float*)d_in[13];
    const float* ro_b     = (const float*)d_in[14];
    float* out = (float*)d_out;

    const int* srcs = edge;
    const int* dsts = edge + E_EDGES;

    float* h  = (float*)d_ws;
    float* xl = h  + (size_t)N_NODES * 64;
    float* xr = xl + (size_t)N_NODES * HC;
    int* counts     = (int*)(xr + (size_t)N_NODES * HC);
    int* row_ptr    = counts + N_NODES;
    int* write_off  = row_ptr + N_NODES + 1;
    int* src_sorted = write_off + N_NODES;
    int* partials   = src_sorted + E_TOT;
    int* block_off  = partials + SCAN_B;
    float2* Ql      = (float2*)(block_off + SCAN_B);   // N float2

    const int T = 256;
    const int gEmbed = (N_NODES * C_DIM + 255) / 256;
    const int gNode  = (N_NODES + 255) / 256;
    const int gEdge  = (E_TOT + 255) / 256;
    const int gLin   = (N_NODES + 15) / 16;
    const int gGat   = (N_NODES + 3) / 4;
    const int gOut   = (G_GRAPHS * OUT_DIM + 255) / 256;

    embed_kernel<<<gEmbed, T, 0, stream>>>(x, embed, h);

    csr_zero_kernel<<<gNode, T, 0, stream>>>(counts);
    csr_count_kernel<<<gEdge, T, 0, stream>>>(dsts, counts);
    scan_partial_kernel<<<SCAN_B, T, 0, stream>>>(counts, row_ptr, partials);
    scan_offsets_kernel<<<1, T, 0, stream>>>(partials, block_off);
    scan_add_kernel<<<SCAN_B, T, 0, stream>>>(row_ptr, block_off, write_off);
    csr_scatter_kernel<<<gEdge, T, 0, stream>>>(srcs, dsts, write_off, src_sorted);

    for (int l = 0; l < L_LAYERS; l++) {
        layer_lin_kernel<<<gLin, T, 0, stream>>>(
            h,
            lin_W + (size_t)l * 64 * 64, lin_b + (size_t)l * 64,
            gat_Wl + (size_t)l * 64 * 128, gat_bl + (size_t)l * 128,
            gat_Wr + (size_t)l * 64 * 128, gat_br + (size_t)l * 128,
            xl, xr);
        ql_kernel<<<gGat, T, 0, stream>>>(
            (const float2*)xl, gat_att + (size_t)l * HC, Ql);
        gat_kernel<<<gGat, T, 0, stream>>>(
            (const float2*)xl, (const float2*)xr, gat_att + (size_t)l * HC,
            row_ptr, src_sorted, Ql, gat_bias + (size_t)l * 64, h);
    }

    zero_out_kernel<<<gOut, T, 0, stream>>>(out);
    readout_kernel<<<gLin, T, 0, stream>>>(h, ro_W, ro_b, batch, out);
}

// Round 7
// 563.624 us; speedup vs baseline: 2.4283x; 2.4283x over previous
//
#include <hip/hip_runtime.h>

#define N_NODES  50000
#define E_EDGES  800000
#define E_TOT    850000   // E + N self-loops
#define H_HEADS  2
#define C_DIM    64
#define HC       128
#define L_LAYERS 3
#define OUT_DIM  128
#define G_GRAPHS 512
#define NEG_SLOPE 0.2f
#define SCAN_B   196      // ceil(N/256)

__device__ __forceinline__ void lds_fence() { asm volatile("" ::: "memory"); }

// ---- h[n][c] = embed[x[n]][c] ----
__global__ void embed_kernel(const int* __restrict__ x, const float* __restrict__ embed,
                             float* __restrict__ h) {
    int i = blockIdx.x * 256 + threadIdx.x;
    if (i >= N_NODES * C_DIM) return;
    int n = i >> 6, c = i & 63;
    h[i] = embed[x[n] * C_DIM + c];
}

// ---- CSR build ----
__global__ void csr_zero_kernel(int* __restrict__ counts) {
    int i = blockIdx.x * 256 + threadIdx.x;
    if (i < N_NODES) counts[i] = 0;
}

__global__ void csr_count_kernel(const int* __restrict__ dsts, int* __restrict__ counts) {
    int e = blockIdx.x * 256 + threadIdx.x;
    if (e >= E_TOT) return;
    int d = (e < E_EDGES) ? dsts[e] : e - E_EDGES;
    atomicAdd(&counts[d], 1);
}

__global__ void scan_partial_kernel(const int* __restrict__ counts, int* __restrict__ row_ptr,
                                    int* __restrict__ partials) {
    __shared__ int wsum[4];
    int i = blockIdx.x * 256 + threadIdx.x;
    int lane = threadIdx.x & 63, wid = threadIdx.x >> 6;
    int cnt = (i < N_NODES) ? counts[i] : 0;
    int v = cnt;
#pragma unroll
    for (int off = 1; off < 64; off <<= 1) {
        int t = __shfl_up(v, off, 64);
        if (lane >= off) v += t;
    }
    if (lane == 63) wsum[wid] = v;
    __syncthreads();
    int woff = 0;
#pragma unroll
    for (int w = 0; w < 4; w++) if (w < wid) woff += wsum[w];
    v += woff;
    if (i < N_NODES) row_ptr[i] = v - cnt;
    if (threadIdx.x == 255) partials[blockIdx.x] = v;
}

__global__ void scan_offsets_kernel(const int* __restrict__ partials, int* __restrict__ block_off) {
    __shared__ int wsum[4];
    int tid = threadIdx.x;
    int lane = tid & 63, wid = tid >> 6;
    int cnt = (tid < SCAN_B) ? partials[tid] : 0;
    int v = cnt;
#pragma unroll
    for (int off = 1; off < 64; off <<= 1) {
        int t = __shfl_up(v, off, 64);
        if (lane >= off) v += t;
    }
    if (lane == 63) wsum[wid] = v;
    __syncthreads();
    int woff = 0;
#pragma unroll
    for (int w = 0; w < 4; w++) if (w < wid) woff += wsum[w];
    v += woff;
    if (tid < SCAN_B) block_off[tid] = v - cnt;
}

__global__ void scan_add_kernel(int* __restrict__ row_ptr, const int* __restrict__ block_off,
                                int* __restrict__ write_off) {
    int i = blockIdx.x * 256 + threadIdx.x;
    if (i < N_NODES) {
        int v = row_ptr[i] + block_off[blockIdx.x];
        row_ptr[i] = v;
        write_off[i] = v;
    }
    if (i == 0) row_ptr[N_NODES] = E_TOT;
}

__global__ void csr_scatter_kernel(const int* __restrict__ srcs, const int* __restrict__ dsts,
                                   int* __restrict__ write_off, int* __restrict__ src_sorted) {
    int e = blockIdx.x * 256 + threadIdx.x;
    if (e >= E_TOT) return;
    int s, d;
    if (e < E_EDGES) { s = srcs[e]; d = dsts[e]; }
    else             { s = d = e - E_EDGES; }
    int pos = atomicAdd(&write_off[d], 1);
    src_sorted[pos] = s;
}

// ---- fused per-layer linears: h2 = relu(h@W+b); xl = h2@Wl+bl; xr = h2@Wr+br.
// (scalar LDS broadcast reads — float4 variant spills, see R6 post-mortem) ----
__global__ void layer_lin_kernel(const float* __restrict__ h,
                                 const float* __restrict__ W, const float* __restrict__ b,
                                 const float* __restrict__ Wl, const float* __restrict__ bl,
                                 const float* __restrict__ Wr, const float* __restrict__ br,
                                 float* __restrict__ xli, float* __restrict__ xri) {
    __shared__ float sH[16 * 64];
    __shared__ float sH2[16 * 64];
    int tid = threadIdx.x;
    int base = blockIdx.x * 16;
#pragma unroll
    for (int i = 0; i < 4; i++) {
        int idx = tid + i * 256;
        int nn = base + (idx >> 6);
        sH[idx] = (nn < N_NODES) ? h[(size_t)nn * 64 + (idx & 63)] : 0.f;
    }
    __syncthreads();
    {
        int c = tid & 63, g = tid >> 6;
        float a0 = b[c], a1 = a0, a2 = a0, a3 = a0;
        for (int k = 0; k < 64; k++) {
            float wv = W[k * 64 + c];
            a0 = fmaf(sH[(g * 4 + 0) * 64 + k], wv, a0);
            a1 = fmaf(sH[(g * 4 + 1) * 64 + k], wv, a1);
            a2 = fmaf(sH[(g * 4 + 2) * 64 + k], wv, a2);
            a3 = fmaf(sH[(g * 4 + 3) * 64 + k], wv, a3);
        }
        sH2[(g * 4 + 0) * 64 + c] = fmaxf(a0, 0.f);
        sH2[(g * 4 + 1) * 64 + c] = fmaxf(a1, 0.f);
        sH2[(g * 4 + 2) * 64 + c] = fmaxf(a2, 0.f);
        sH2[(g * 4 + 3) * 64 + c] = fmaxf(a3, 0.f);
    }
    __syncthreads();
    {
        int j = tid & 127, gg = tid >> 7;
        float accl[8], accr[8];
#pragma unroll
        for (int n = 0; n < 8; n++) { accl[n] = bl[j]; accr[n] = br[j]; }
        for (int k = 0; k < 64; k++) {
            float wl = Wl[k * 128 + j], wr = Wr[k * 128 + j];
#pragma unroll
            for (int n = 0; n < 8; n++) {
                float hv = sH2[(gg * 8 + n) * 64 + k];
                accl[n] = fmaf(hv, wl, accl[n]);
                accr[n] = fmaf(hv, wr, accr[n]);
            }
        }
        int hh = j >> 6, c = j & 63;
#pragma unroll
        for (int n = 0; n < 8; n++) {
            int node = base + gg * 8 + n;
            if (node < N_NODES) {
                size_t o = (size_t)node * 128 + c * 2 + hh;
                xli[o] = accl[n];
                xri[o] = accr[n];
            }
        }
    }
}

// ---- Ql[n][h] = sum_c leaky(a_hc * xl[n,h,c]) — node-separable softmax-shift bound ----
__global__ void ql_kernel(const float2* __restrict__ xl2, const float* __restrict__ att,
                          float2* __restrict__ Ql) {
    int w = threadIdx.x >> 6;
    int n = blockIdx.x * 4 + w;
    if (n >= N_NODES) return;
    int lane = threadIdx.x & 63;
    float2 v = xl2[(size_t)n * 64 + lane];
    float px = att[lane] * v.x, py = att[64 + lane] * v.y;
    float qx = fmaxf(px, NEG_SLOPE * px);   // leaky(p) = 0.6p + 0.4|p|
    float qy = fmaxf(py, NEG_SLOPE * py);
#pragma unroll
    for (int off = 32; off; off >>= 1) {
        qx += __shfl_xor(qx, off, 64);
        qy += __shfl_xor(qy, off, 64);
    }
    if (lane == 0) Ql[n] = make_float2(qx, qy);
}

// ---- GATv2 edge phase: one wave per dst node, lane = channel, float2 = both heads.
// Softmax shift m = Qr[d] + max_in Ql[s] precomputed -> no online rescale, no max pass. ----
__global__ void gat_kernel(const float2* __restrict__ xl2, const float2* __restrict__ xr2,
                           const float* __restrict__ att, const int* __restrict__ row_ptr,
                           const int* __restrict__ src_sorted, const float2* __restrict__ Ql,
                           const float* __restrict__ bias, float* __restrict__ h_out) {
    __shared__ __align__(16) float cbuf[4][8 * 132];
    __shared__ float2 wbuf[4][8];
    int w = threadIdx.x >> 6;
    int d = blockIdx.x * 4 + w;
    if (d >= N_NODES) return;
    int lane = threadIdx.x & 63;
    int r0 = row_ptr[d], r1 = row_ptr[d + 1];
    float2 vr = xr2[(size_t)d * 64 + lane];
    float ax = att[lane], ay = att[64 + lane];
    float* cb = cbuf[w];
    float2* wb = wbuf[w];
    int e_of = lane >> 3, p = lane & 7;

    // Qr[d] = sum_c leaky(a_c * vr_c) per head (upper-bound piece of dst)
    float prx = ax * vr.x, pry = ay * vr.y;
    float qrx = fmaxf(prx, NEG_SLOPE * prx);
    float qry = fmaxf(pry, NEG_SLOPE * pry);
    // max of Ql over incoming srcs
    float mqx = -INFINITY, mqy = -INFINITY;
    for (int base = r0; base < r1; base += 64) {
        int a = base + lane;
        if (a < r1) {
            float2 q = Ql[src_sorted[a]];
            mqx = fmaxf(mqx, q.x);
            mqy = fmaxf(mqy, q.y);
        }
    }
#pragma unroll
    for (int off = 32; off; off >>= 1) {
        qrx += __shfl_xor(qrx, off, 64);
        qry += __shfl_xor(qry, off, 64);
        mqx = fmaxf(mqx, __shfl_xor(mqx, off, 64));
        mqy = fmaxf(mqy, __shfl_xor(mqy, off, 64));
    }
    float mx = mqx + qrx, my = mqy + qry;   // guaranteed >= every incoming score

    float dpx = 0.f, dpy = 0.f;
    float accx = 0.f, accy = 0.f;

    for (int base = r0; base < r1; base += 64) {
        int a = base + lane;
        int idx = src_sorted[(a < r1) ? a : (r1 - 1)];
        for (int cbase = 0; cbase < 64 && base + cbase < r1; cbase += 8) {
            int rem = r1 - base - cbase;
            float2 vl[8];
#pragma unroll
            for (int e = 0; e < 8; e++) {
                int sv = __builtin_amdgcn_readlane(idx, cbase + e);
                int s = (e < rem) ? sv : d;
                vl[e] = xl2[(size_t)s * 64 + lane];
            }
#pragma unroll
            for (int e = 0; e < 8; e++) {
                float vx = vl[e].x + vr.x, vy = vl[e].y + vr.y;
                vx = fmaxf(vx, vx * NEG_SLOPE);
                vy = fmaxf(vy, vy * NEG_SLOPE);
                *(float2*)&cb[e * 132 + 2 * lane] = make_float2(vx * ax, vy * ay);
            }
            lds_fence();
            float sx = 0.f, sy = 0.f;
            {
                const float4* row = (const float4*)&cb[e_of * 132 + p * 16];
#pragma unroll
                for (int j = 0; j < 4; j++) {
                    float4 f = row[j];
                    sx += f.x + f.z;
                    sy += f.y + f.w;
                }
            }
            lds_fence();
#pragma unroll
            for (int off = 1; off <= 4; off <<= 1) {
                sx += __shfl_xor(sx, off, 64);
                sy += __shfl_xor(sy, off, 64);
            }
            if (e_of >= rem) { sx = -INFINITY; sy = -INFINITY; }  // exp -> 0
            float wx = __expf(sx - mx), wy = __expf(sy - my);
            dpx += wx; dpy += wy;
            if (p == 0) wb[e_of] = make_float2(wx, wy);
            lds_fence();
#pragma unroll
            for (int e = 0; e < 8; e++) {
                float2 wv = wb[e];
                accx = fmaf(wv.x, vl[e].x, accx);
                accy = fmaf(wv.y, vl[e].y, accy);
            }
            lds_fence();
        }
    }
#pragma unroll
    for (int off = 32; off; off >>= 1) {
        dpx += __shfl_xor(dpx, off, 64);
        dpy += __shfl_xor(dpy, off, 64);
    }
    h_out[(size_t)d * 64 + lane] = (accx / dpx + accy / dpy) * 4.0f + bias[lane];
}

__global__ void zero_out_kernel(float* __restrict__ out) {
    int i = blockIdx.x * 256 + threadIdx.x;
    if (i < G_GRAPHS * OUT_DIM) out[i] = 0.f;
}

// ---- readout GEMM fused with per-graph segment sum (scalar LDS reads — see R6) ----
__global__ void readout_kernel(const float* __restrict__ h, const float* __restrict__ W,
                               const float* __restrict__ b, const int* __restrict__ batch,
                               float* __restrict__ out) {
    __shared__ float sH[16 * 64];
    __shared__ int sB[16];
    int tid = threadIdx.x;
    int base = blockIdx.x * 16;
#pragma unroll
    for (int i = 0; i < 4; i++) {
        int idx = tid + i * 256;
        int nn = base + (idx >> 6);
        sH[idx] = (nn < N_NODES) ? h[(size_t)nn * 64 + (idx & 63)] : 0.f;
    }
    if (tid < 16) sB[tid] = (base + tid < N_NODES) ? batch[base + tid] : -1;
    __syncthreads();
    int j = tid & 127, gg = tid >> 7;
    float acc[8];
#pragma unroll
    for (int n = 0; n < 8; n++) acc[n] = b[j];
    for (int k = 0; k < 64; k++) {
        float wv = W[k * OUT_DIM + j];
#pragma unroll
        for (int n = 0; n < 8; n++) acc[n] = fmaf(sH[(gg * 8 + n) * 64 + k], wv, acc[n]);
    }
    float run = 0.f; int curb = -2;
#pragma unroll
    for (int n = 0; n < 8; n++) {
        int node = base + gg * 8 + n;
        int bb = (node < N_NODES) ? sB[gg * 8 + n] : -1;
        if (bb != curb) {
            if (curb >= 0) atomicAdd(&out[curb * OUT_DIM + j], run);
            run = 0.f; curb = bb;
        }
        if (bb >= 0) run += acc[n];
    }
    if (curb >= 0) atomicAdd(&out[curb * OUT_DIM + j], run);
}

extern "C" void kernel_launch(void* const* d_in, const int* in_sizes, int n_in,
                              void* d_out, int out_size, void* d_ws, size_t ws_size,
                              hipStream_t stream) {
    const int*   x        = (const int*)d_in[0];
    const int*   edge     = (const int*)d_in[1];
    const int*   batch    = (const int*)d_in[2];
    const float* embed    = (const float*)d_in[4];
    const float* lin_W    = (const float*)d_in[5];
    const float* lin_b    = (const float*)d_in[6];
    const float* gat_Wl   = (const float*)d_in[7];
    const float* gat_bl   = (const float*)d_in[8];
    const float* gat_Wr   = (const float*)d_in[9];
    const float* gat_br   = (const float*)d_in[10];
    const float* gat_att  = (const float*)d_in[11];
    const float* gat_bias = (const float*)d_in[12];
    const float* ro_W     = (const float*)d_in[13];
    const float* ro_b     = (const float*)d_in[14];
    float* out = (float*)d_out;

    const int* srcs = edge;
    const int* dsts = edge + E_EDGES;

    float* h  = (float*)d_ws;
    float* xl = h  + (size_t)N_NODES * 64;
    float* xr = xl + (size_t)N_NODES * HC;
    int* counts     = (int*)(xr + (size_t)N_NODES * HC);
    int* row_ptr    = counts + N_NODES;
    int* write_off  = row_ptr + N_NODES + 1;
    int* src_sorted = write_off + N_NODES;
    int* partials   = src_sorted + E_TOT;
    int* block_off  = partials + SCAN_B;
    float2* Ql      = (float2*)(block_off + SCAN_B);   // N float2

    const int T = 256;
    const int gEmbed = (N_NODES * C_DIM + 255) / 256;
    const int gNode  = (N_NODES + 255) / 256;
    const int gEdge  = (E_TOT + 255) / 256;
    const int gLin   = (N_NODES + 15) / 16;
    const int gGat   = (N_NODES + 3) / 4;
    const int gOut   = (G_GRAPHS * OUT_DIM + 255) / 256;

    embed_kernel<<<gEmbed, T, 0, stream>>>(x, embed, h);

    csr_zero_kernel<<<gNode, T, 0, stream>>>(counts);
    csr_count_kernel<<<gEdge, T, 0, stream>>>(dsts, counts);
    scan_partial_kernel<<<SCAN_B, T, 0, stream>>>(counts, row_ptr, partials);
    scan_offsets_kernel<<<1, T, 0, stream>>>(partials, block_off);
    scan_add_kernel<<<SCAN_B, T, 0, stream>>>(row_ptr, block_off, write_off);
    csr_scatter_kernel<<<gEdge, T, 0, stream>>>(srcs, dsts, write_off, src_sorted);

    for (int l = 0; l < L_LAYERS; l++) {
        layer_lin_kernel<<<gLin, T, 0, stream>>>(
            h,
            lin_W + (size_t)l * 64 * 64, lin_b + (size_t)l * 64,
            gat_Wl + (size_t)l * 64 * 128, gat_bl + (size_t)l * 128,
            gat_Wr + (size_t)l * 64 * 128, gat_br + (size_t)l * 128,
            xl, xr);
        ql_kernel<<<gGat, T, 0, stream>>>(
            (const float2*)xl, gat_att + (size_t)l * HC, Ql);
        gat_kernel<<<gGat, T, 0, stream>>>(
            (const float2*)xl, (const float2*)xr, gat_att + (size_t)l * HC,
            row_ptr, src_sorted, Ql, gat_bias + (size_t)l * 64, h);
    }

    zero_out_kernel<<<gOut, T, 0, stream>>>(out);
    readout_kernel<<<gLin, T, 0, stream>>>(h, ro_W, ro_b, batch, out);
}

// Round 8
// 549.781 us; speedup vs baseline: 2.4894x; 1.0252x over previous
//
#include <hip/hip_runtime.h>

#define N_NODES  50000
#define E_EDGES  800000
#define E_TOT    850000   // E + N self-loops
#define H_HEADS  2
#define C_DIM    64
#define HC       128
#define L_LAYERS 3
#define OUT_DIM  128
#define G_GRAPHS 512
#define NEG_SLOPE 0.2f
#define SCAN_B   196      // ceil(N/256)

// ---- DPP / swizzle reduction helpers (sum/max over 32-lane head groups) ----
// quad_perm xor1 = [1,0,3,2] -> 0xB1 ; quad_perm xor2 = [2,3,0,1] -> 0x4E
// row_half_mirror = 0x141 (pairs 4-groups within 8) ; row_mirror = 0x140 (pairs 8-groups within 16)
// ds_swizzle 0x401F = lane ^ 16 within each 32-lane group
template <int CTRL>
__device__ __forceinline__ float dpp_add(float x) {
    int y = __builtin_amdgcn_update_dpp(0, __float_as_int(x), CTRL, 0xF, 0xF, true);
    return x + __int_as_float(y);
}
template <int CTRL>
__device__ __forceinline__ float dpp_max(float x) {
    int y = __builtin_amdgcn_update_dpp(0, __float_as_int(x), CTRL, 0xF, 0xF, true);
    return fmaxf(x, __int_as_float(y));
}
__device__ __forceinline__ float swz16_add(float x) {
    return x + __int_as_float(__builtin_amdgcn_ds_swizzle(__float_as_int(x), 0x401F));
}
__device__ __forceinline__ float swz16_max(float x) {
    return fmaxf(x, __int_as_float(__builtin_amdgcn_ds_swizzle(__float_as_int(x), 0x401F)));
}
__device__ __forceinline__ float reduce32_add(float x) {
    x = dpp_add<0xB1>(x);   // xor1
    x = dpp_add<0x4E>(x);   // xor2
    x = dpp_add<0x141>(x);  // 4<->4 within 8
    x = dpp_add<0x140>(x);  // 8<->8 within 16
    return swz16_add(x);    // 16<->16 within 32
}
__device__ __forceinline__ float reduce32_max(float x) {
    x = dpp_max<0xB1>(x);
    x = dpp_max<0x4E>(x);
    x = dpp_max<0x141>(x);
    x = dpp_max<0x140>(x);
    return swz16_max(x);
}

// ---- h[n][c] = embed[x[n]][c] ----
__global__ void embed_kernel(const int* __restrict__ x, const float* __restrict__ embed,
                             float* __restrict__ h) {
    int i = blockIdx.x * 256 + threadIdx.x;
    if (i >= N_NODES * C_DIM) return;
    int n = i >> 6, c = i & 63;
    h[i] = embed[x[n] * C_DIM + c];
}

// ---- CSR build ----
__global__ void csr_zero_kernel(int* __restrict__ counts) {
    int i = blockIdx.x * 256 + threadIdx.x;
    if (i < N_NODES) counts[i] = 0;
}

__global__ void csr_count_kernel(const int* __restrict__ dsts, int* __restrict__ counts) {
    int e = blockIdx.x * 256 + threadIdx.x;
    if (e >= E_TOT) return;
    int d = (e < E_EDGES) ? dsts[e] : e - E_EDGES;
    atomicAdd(&counts[d], 1);
}

__global__ void scan_partial_kernel(const int* __restrict__ counts, int* __restrict__ row_ptr,
                                    int* __restrict__ partials) {
    __shared__ int wsum[4];
    int i = blockIdx.x * 256 + threadIdx.x;
    int lane = threadIdx.x & 63, wid = threadIdx.x >> 6;
    int cnt = (i < N_NODES) ? counts[i] : 0;
    int v = cnt;
#pragma unroll
    for (int off = 1; off < 64; off <<= 1) {
        int t = __shfl_up(v, off, 64);
        if (lane >= off) v += t;
    }
    if (lane == 63) wsum[wid] = v;
    __syncthreads();
    int woff = 0;
#pragma unroll
    for (int w = 0; w < 4; w++) if (w < wid) woff += wsum[w];
    v += woff;
    if (i < N_NODES) row_ptr[i] = v - cnt;
    if (threadIdx.x == 255) partials[blockIdx.x] = v;
}

__global__ void scan_offsets_kernel(const int* __restrict__ partials, int* __restrict__ block_off) {
    __shared__ int wsum[4];
    int tid = threadIdx.x;
    int lane = tid & 63, wid = tid >> 6;
    int cnt = (tid < SCAN_B) ? partials[tid] : 0;
    int v = cnt;
#pragma unroll
    for (int off = 1; off < 64; off <<= 1) {
        int t = __shfl_up(v, off, 64);
        if (lane >= off) v += t;
    }
    if (lane == 63) wsum[wid] = v;
    __syncthreads();
    int woff = 0;
#pragma unroll
    for (int w = 0; w < 4; w++) if (w < wid) woff += wsum[w];
    v += woff;
    if (tid < SCAN_B) block_off[tid] = v - cnt;
}

__global__ void scan_add_kernel(int* __restrict__ row_ptr, const int* __restrict__ block_off,
                                int* __restrict__ write_off) {
    int i = blockIdx.x * 256 + threadIdx.x;
    if (i < N_NODES) {
        int v = row_ptr[i] + block_off[blockIdx.x];
        row_ptr[i] = v;
        write_off[i] = v;
    }
    if (i == 0) row_ptr[N_NODES] = E_TOT;
}

__global__ void csr_scatter_kernel(const int* __restrict__ srcs, const int* __restrict__ dsts,
                                   int* __restrict__ write_off, int* __restrict__ src_sorted) {
    int e = blockIdx.x * 256 + threadIdx.x;
    if (e >= E_TOT) return;
    int s, d;
    if (e < E_EDGES) { s = srcs[e]; d = dsts[e]; }
    else             { s = d = e - E_EDGES; }
    int pos = atomicAdd(&write_off[d], 1);
    src_sorted[pos] = s;
}

// ---- fused per-layer linears: h2 = relu(h@W+b); xl = h2@Wl+bl; xr = h2@Wr+br.
// Output layout: plain [n][h*64+c] (scalar LDS broadcast reads — float4 spills, R6) ----
__global__ void layer_lin_kernel(const float* __restrict__ h,
                                 const float* __restrict__ W, const float* __restrict__ b,
                                 const float* __restrict__ Wl, const float* __restrict__ bl,
                                 const float* __restrict__ Wr, const float* __restrict__ br,
                                 float* __restrict__ xli, float* __restrict__ xri) {
    __shared__ float sH[16 * 64];
    __shared__ float sH2[16 * 64];
    int tid = threadIdx.x;
    int base = blockIdx.x * 16;
#pragma unroll
    for (int i = 0; i < 4; i++) {
        int idx = tid + i * 256;
        int nn = base + (idx >> 6);
        sH[idx] = (nn < N_NODES) ? h[(size_t)nn * 64 + (idx & 63)] : 0.f;
    }
    __syncthreads();
    {
        int c = tid & 63, g = tid >> 6;
        float a0 = b[c], a1 = a0, a2 = a0, a3 = a0;
        for (int k = 0; k < 64; k++) {
            float wv = W[k * 64 + c];
            a0 = fmaf(sH[(g * 4 + 0) * 64 + k], wv, a0);
            a1 = fmaf(sH[(g * 4 + 1) * 64 + k], wv, a1);
            a2 = fmaf(sH[(g * 4 + 2) * 64 + k], wv, a2);
            a3 = fmaf(sH[(g * 4 + 3) * 64 + k], wv, a3);
        }
        sH2[(g * 4 + 0) * 64 + c] = fmaxf(a0, 0.f);
        sH2[(g * 4 + 1) * 64 + c] = fmaxf(a1, 0.f);
        sH2[(g * 4 + 2) * 64 + c] = fmaxf(a2, 0.f);
        sH2[(g * 4 + 3) * 64 + c] = fmaxf(a3, 0.f);
    }
    __syncthreads();
    {
        int j = tid & 127, gg = tid >> 7;
        float accl[8], accr[8];
#pragma unroll
        for (int n = 0; n < 8; n++) { accl[n] = bl[j]; accr[n] = br[j]; }
        for (int k = 0; k < 64; k++) {
            float wl = Wl[k * 128 + j], wr = Wr[k * 128 + j];
#pragma unroll
            for (int n = 0; n < 8; n++) {
                float hv = sH2[(gg * 8 + n) * 64 + k];
                accl[n] = fmaf(hv, wl, accl[n]);
                accr[n] = fmaf(hv, wr, accr[n]);
            }
        }
#pragma unroll
        for (int n = 0; n < 8; n++) {
            int node = base + gg * 8 + n;
            if (node < N_NODES) {
                size_t o = (size_t)node * 128 + j;   // plain layout
                xli[o] = accl[n];
                xri[o] = accr[n];
            }
        }
    }
}

// ---- Ql[n] = {sum_c leaky(a_0c xl[n,0,c]), sum_c leaky(a_1c xl[n,1,c])} ----
__global__ void ql_kernel(const float2* __restrict__ xl2, const float2* __restrict__ att2,
                          float2* __restrict__ Ql) {
    int w = threadIdx.x >> 6;
    int n = blockIdx.x * 4 + w;
    if (n >= N_NODES) return;
    int lane = threadIdx.x & 63;
    float2 v = xl2[(size_t)n * 64 + lane];
    float2 a = att2[lane];
    float px = a.x * v.x, py = a.y * v.y;
    float q = fmaxf(px, NEG_SLOPE * px) + fmaxf(py, NEG_SLOPE * py);
    q = reduce32_add(q);                   // lanes<32: head0 total; >=32: head1 total
    float qh1 = __shfl_xor(q, 32, 64);
    if (lane == 0) Ql[n] = make_float2(q, qh1);
}

// ---- GATv2 edge phase v3: one wave per dst node, lane = (head, channel-pair).
// DPP 32-lane reductions, zero LDS, per-edge-independent chains (shift via Ql). ----
__global__ void gat_kernel(const float2* __restrict__ xl2, const float2* __restrict__ xr2,
                           const float2* __restrict__ att2, const int* __restrict__ row_ptr,
                           const int* __restrict__ src_sorted, const float2* __restrict__ Ql,
                           const float* __restrict__ bias, float* __restrict__ h_out) {
    int w = threadIdx.x >> 6;
    int d = blockIdx.x * 4 + w;
    if (d >= N_NODES) return;
    int lane = threadIdx.x & 63;
    int r0 = row_ptr[d], r1 = row_ptr[d + 1];
    float2 vr = xr2[(size_t)d * 64 + lane];
    float2 a = att2[lane];

    // Qr per head (32-group reduce; each lane ends with its own head's total)
    float prx = a.x * vr.x, pry = a.y * vr.y;
    float qr = fmaxf(prx, NEG_SLOPE * prx) + fmaxf(pry, NEG_SLOPE * pry);
    qr = reduce32_add(qr);

    // per-head max of Ql over incoming edges (each lane scans a stripe, tracks BOTH heads)
    float mqx = -INFINITY, mqy = -INFINITY;
    for (int base = r0; base < r1; base += 64) {
        int aa = base + lane;
        if (aa < r1) {
            float2 q = Ql[src_sorted[aa]];
            mqx = fmaxf(mqx, q.x);
            mqy = fmaxf(mqy, q.y);
        }
    }
    mqx = reduce32_max(mqx); mqx = fmaxf(mqx, __shfl_xor(mqx, 32, 64));
    mqy = reduce32_max(mqy); mqy = fmaxf(mqy, __shfl_xor(mqy, 32, 64));
    float m = ((lane < 32) ? mqx : mqy) + qr;   // per-lane (per-head) shift, >= all scores

    float2 acc = make_float2(0.f, 0.f);
    float dp = 0.f;

    for (int base = r0; base < r1; base += 64) {
        int aa = base + lane;
        int idx = src_sorted[(aa < r1) ? aa : (r1 - 1)];   // coalesced stage
        for (int cbase = 0; cbase < 64 && base + cbase < r1; cbase += 8) {
            int rem = r1 - base - cbase;                   // wave-uniform, >=1
            float2 vl[8];
#pragma unroll
            for (int e = 0; e < 8; e++) {
                int sv = __builtin_amdgcn_readlane(idx, cbase + e);
                int s = (e < rem) ? sv : d;
                vl[e] = xl2[(size_t)s * 64 + lane];        // 512 B contiguous per edge
            }
            float sc[8];
#pragma unroll
            for (int e = 0; e < 8; e++) {
                float vx = vl[e].x + vr.x, vy = vl[e].y + vr.y;
                vx = fmaxf(vx, NEG_SLOPE * vx);
                vy = fmaxf(vy, NEG_SLOPE * vy);
                sc[e] = reduce32_add(fmaf(vx, a.x, vy * a.y));  // independent chains
            }
#pragma unroll
            for (int e = 0; e < 8; e++) {
                float s_ = (e < rem) ? sc[e] : -INFINITY;
                float wgt = __expf(s_ - m);                // group-uniform per head
                dp += wgt;
                acc.x = fmaf(wgt, vl[e].x, acc.x);
                acc.y = fmaf(wgt, vl[e].y, acc.y);
            }
        }
    }
    // dp is uniform within each 32-lane head group; combine heads across the 32-boundary
    float ox = acc.x / dp, oy = acc.y / dp;
    float oxp = __shfl_xor(ox, 32, 64);
    float oyp = __shfl_xor(oy, 32, 64);
    if (lane < 32) {
        int c = lane * 2;
        float2 o;
        o.x = (ox + oxp) * 0.5f + bias[c];
        o.y = (oy + oyp) * 0.5f + bias[c + 1];
        *(float2*)&h_out[(size_t)d * 64 + c] = o;
    }
}

__global__ void zero_out_kernel(float* __restrict__ out) {
    int i = blockIdx.x * 256 + threadIdx.x;
    if (i < G_GRAPHS * OUT_DIM) out[i] = 0.f;
}

// ---- readout GEMM fused with per-graph segment sum (scalar LDS reads — see R6) ----
__global__ void readout_kernel(const float* __restrict__ h, const float* __restrict__ W,
                               const float* __restrict__ b, const int* __restrict__ batch,
                               float* __restrict__ out) {
    __shared__ float sH[16 * 64];
    __shared__ int sB[16];
    int tid = threadIdx.x;
    int base = blockIdx.x * 16;
#pragma unroll
    for (int i = 0; i < 4; i++) {
        int idx = tid + i * 256;
        int nn = base + (idx >> 6);
        sH[idx] = (nn < N_NODES) ? h[(size_t)nn * 64 + (idx & 63)] : 0.f;
    }
    if (tid < 16) sB[tid] = (base + tid < N_NODES) ? batch[base + tid] : -1;
    __syncthreads();
    int j = tid & 127, gg = tid >> 7;
    float acc[8];
#pragma unroll
    for (int n = 0; n < 8; n++) acc[n] = b[j];
    for (int k = 0; k < 64; k++) {
        float wv = W[k * OUT_DIM + j];
#pragma unroll
        for (int n = 0; n < 8; n++) acc[n] = fmaf(sH[(gg * 8 + n) * 64 + k], wv, acc[n]);
    }
    float run = 0.f; int curb = -2;
#pragma unroll
    for (int n = 0; n < 8; n++) {
        int node = base + gg * 8 + n;
        int bb = (node < N_NODES) ? sB[gg * 8 + n] : -1;
        if (bb != curb) {
            if (curb >= 0) atomicAdd(&out[curb * OUT_DIM + j], run);
            run = 0.f; curb = bb;
        }
        if (bb >= 0) run += acc[n];
    }
    if (curb >= 0) atomicAdd(&out[curb * OUT_DIM + j], run);
}

extern "C" void kernel_launch(void* const* d_in, const int* in_sizes, int n_in,
                              void* d_out, int out_size, void* d_ws, size_t ws_size,
                              hipStream_t stream) {
    const int*   x        = (const int*)d_in[0];
    const int*   edge     = (const int*)d_in[1];
    const int*   batch    = (const int*)d_in[2];
    const float* embed    = (const float*)d_in[4];
    const float* lin_W    = (const float*)d_in[5];
    const float* lin_b    = (const float*)d_in[6];
    const float* gat_Wl   = (const float*)d_in[7];
    const float* gat_bl   = (const float*)d_in[8];
    const float* gat_Wr   = (const float*)d_in[9];
    const float* gat_br   = (const float*)d_in[10];
    const float* gat_att  = (const float*)d_in[11];
    const float* gat_bias = (const float*)d_in[12];
    const float* ro_W     = (const float*)d_in[13];
    const float* ro_b     = (const float*)d_in[14];
    float* out = (float*)d_out;

    const int* srcs = edge;
    const int* dsts = edge + E_EDGES;

    float* h  = (float*)d_ws;
    float* xl = h  + (size_t)N_NODES * 64;
    float* xr = xl + (size_t)N_NODES * HC;
    int* counts     = (int*)(xr + (size_t)N_NODES * HC);
    int* row_ptr    = counts + N_NODES;
    int* write_off  = row_ptr + N_NODES + 1;
    int* src_sorted = write_off + N_NODES;
    int* partials   = src_sorted + E_TOT;
    int* block_off  = partials + SCAN_B;
    float2* Ql      = (float2*)(block_off + SCAN_B);   // N float2

    const int T = 256;
    const int gEmbed = (N_NODES * C_DIM + 255) / 256;
    const int gNode  = (N_NODES + 255) / 256;
    const int gEdge  = (E_TOT + 255) / 256;
    const int gLin   = (N_NODES + 15) / 16;
    const int gGat   = (N_NODES + 3) / 4;
    const int gOut   = (G_GRAPHS * OUT_DIM + 255) / 256;

    embed_kernel<<<gEmbed, T, 0, stream>>>(x, embed, h);

    csr_zero_kernel<<<gNode, T, 0, stream>>>(counts);
    csr_count_kernel<<<gEdge, T, 0, stream>>>(dsts, counts);
    scan_partial_kernel<<<SCAN_B, T, 0, stream>>>(counts, row_ptr, partials);
    scan_offsets_kernel<<<1, T, 0, stream>>>(partials, block_off);
    scan_add_kernel<<<SCAN_B, T, 0, stream>>>(row_ptr, block_off, write_off);
    csr_scatter_kernel<<<gEdge, T, 0, stream>>>(srcs, dsts, write_off, src_sorted);

    for (int l = 0; l < L_LAYERS; l++) {
        layer_lin_kernel<<<gLin, T, 0, stream>>>(
            h,
            lin_W + (size_t)l * 64 * 64, lin_b + (size_t)l * 64,
            gat_Wl + (size_t)l * 64 * 128, gat_bl + (size_t)l * 128,
            gat_Wr + (size_t)l * 64 * 128, gat_br + (size_t)l * 128,
            xl, xr);
        ql_kernel<<<gGat, T, 0, stream>>>(
            (const float2*)xl, (const float2*)(gat_att + (size_t)l * HC), Ql);
        gat_kernel<<<gGat, T, 0, stream>>>(
            (const float2*)xl, (const float2*)xr, (const float2*)(gat_att + (size_t)l * HC),
            row_ptr, src_sorted, Ql, gat_bias + (size_t)l * 64, h);
    }

    zero_out_kernel<<<gOut, T, 0, stream>>>(out);
    readout_kernel<<<gLin, T, 0, stream>>>(h, ro_W, ro_b, batch, out);
}